// Round 1
// baseline (129.534 us; speedup 1.0000x reference)
//
#include <hip/hip_runtime.h>

#define IMG_W 256
#define IMG_H 256
#define N_PTS 320
#define VD 256
#define VH 256
#define VW 256
#define NCHUNK 4
#define PPC (N_PTS / NCHUNK)   // 80 depth samples per chunk

// Block: (64, NCHUNK). Wave = 64 consecutive w (x) pixels at one depth-chunk.
__global__ __launch_bounds__(256) void render_kernel(
    const float* __restrict__ vol,    // (256,256,256), z-major: [(z*256+y)*256+x]
    const float* __restrict__ Rm,     // 3x3 row-major
    const float* __restrict__ Tv,     // 3
    const float* __restrict__ focal,  // 1
    float* __restrict__ out,          // 65536, layout out[w*IMG_H + h]
    unsigned int* __restrict__ maxbits)
{
    const int tx = threadIdx.x;            // 0..63
    const int ty = threadIdx.y;            // chunk 0..3
    const int w  = blockIdx.x * 64 + tx;   // pixel column (xs index)
    const int h  = blockIdx.y;             // pixel row (ys index)

    // xs = linspace(a, -a, 256), a = 1 - 1/256
    const float a  = 1.0f - 1.0f / IMG_W;
    const float gx = a - (2.0f * a / (IMG_W - 1)) * (float)w;
    const float gy = a - (2.0f * a / (IMG_H - 1)) * (float)h;

    const float f  = focal[0];
    const float ux = gx / f, uy = gy / f;

    const float R00 = Rm[0], R01 = Rm[1], R02 = Rm[2];
    const float R10 = Rm[3], R11 = Rm[4], R12 = Rm[5];
    const float R20 = Rm[6], R21 = Rm[7], R22 = Rm[8];
    const float Tx = Tv[0], Ty = Tv[1], Tz = Tv[2];

    // world coords are affine in depth d: wx = Bx*d + Ax, etc.
    const float Bx = R00 * ux + R01 * uy + R02;
    const float By = R10 * ux + R11 * uy + R12;
    const float Bz = R20 * ux + R21 * uy + R22;
    const float Ax = -(R00 * Tx + R01 * Ty + R02 * Tz);
    const float Ay = -(R10 * Tx + R11 * Ty + R12 * Tz);
    const float Az = -(R20 * Tx + R21 * Ty + R22 * Tz);

    // half extents: voxel = 2/256; hx = voxel*(W-1)/2
    const float voxel = 2.0f / 256.0f;
    const float hx = voxel * (VW - 1) * 0.5f;
    const float hy = voxel * (VH - 1) * 0.5f;
    const float hz = voxel * (VD - 1) * 0.5f;

    // voxel-space coords: fx = (wx/hx + 1) * 0.5 * (W-1)  -> affine in d
    const float sxc = 0.5f * (VW - 1) / hx, oxc = 0.5f * (VW - 1);
    const float syc = 0.5f * (VH - 1) / hy, oyc = 0.5f * (VH - 1);
    const float szc = 0.5f * (VD - 1) / hz, ozc = 0.5f * (VD - 1);
    const float fBx = Bx * sxc, fAx = Ax * sxc + oxc;
    const float fBy = By * syc, fAy = Ay * syc + oyc;
    const float fBz = Bz * szc, fAz = Az * szc + ozc;

    const float dstep = 6.0f / (N_PTS - 1);

    float S = 0.0f;   // chunk-local weighted feature sum
    float A = 1.0f;   // chunk-local transmittance product (== opacity product)

    #pragma unroll 4
    for (int i = 0; i < PPC; ++i) {
        const int   p = ty * PPC + i;
        const float d = 3.0f + (float)p * dstep;

        const float fx = fmaf(fBx, d, fAx);
        const float fy = fmaf(fBy, d, fAy);
        const float fz = fmaf(fBz, d, fAz);

        const float flx = floorf(fx), fly = floorf(fy), flz = floorf(fz);
        const int ix0 = (int)flx, iy0 = (int)fly, iz0 = (int)flz;

        float dens = 0.0f, feat = 0.0f;
        if (ix0 >= -1 && ix0 < VW && iy0 >= -1 && iy0 < VH && iz0 >= -1 && iz0 < VD) {
            const float frx = fx - flx, fry = fy - fly, frz = fz - flz;
            float wx0 = 1.0f - frx, wx1 = frx;
            float wy0 = 1.0f - fry, wy1 = fry;
            float wz0 = 1.0f - frz, wz1 = frz;
            if (ix0 < 0)       wx0 = 0.0f;
            if (ix0 + 1 >= VW) wx1 = 0.0f;
            if (iy0 < 0)       wy0 = 0.0f;
            if (iy0 + 1 >= VH) wy1 = 0.0f;
            if (iz0 < 0)       wz0 = 0.0f;
            if (iz0 + 1 >= VD) wz1 = 0.0f;

            const int cx0 = max(ix0, 0), cx1 = min(ix0 + 1, VW - 1);
            const int cy0 = max(iy0, 0), cy1 = min(iy0 + 1, VH - 1);
            const int cz0 = max(iz0, 0), cz1 = min(iz0 + 1, VD - 1);

            const int zb0 = cz0 * (VH * VW), zb1 = cz1 * (VH * VW);
            const int yb0 = cy0 * VW,        yb1 = cy1 * VW;

            const float v000 = vol[zb0 + yb0 + cx0];
            const float v001 = vol[zb0 + yb0 + cx1];
            const float v010 = vol[zb0 + yb1 + cx0];
            const float v011 = vol[zb0 + yb1 + cx1];
            const float v100 = vol[zb1 + yb0 + cx0];
            const float v101 = vol[zb1 + yb0 + cx1];
            const float v110 = vol[zb1 + yb1 + cx0];
            const float v111 = vol[zb1 + yb1 + cx1];

            const float w00 = wy0 * wz0, w01 = wy1 * wz0;
            const float w10 = wy0 * wz1, w11 = wy1 * wz1;
            const float c000 = wx0 * w00, c001 = wx1 * w00;
            const float c010 = wx0 * w01, c011 = wx1 * w01;
            const float c100 = wx0 * w10, c101 = wx1 * w10;
            const float c110 = wx0 * w11, c111 = wx1 * w11;

            feat = c000 * v000 + c001 * v001 + c010 * v010 + c011 * v011
                 + c100 * v100 + c101 * v101 + c110 * v110 + c111 * v111;
            dens = 0.1f * (c000 + c001 + c010 + c011 + c100 + c101 + c110 + c111);
        }

        // weights_p = dens_p * prod_{q<p}(1+eps-dens_q); (1+1e-10) == 1.0f in f32
        S = fmaf(dens * A, feat, S);
        A *= (1.0f - dens);
    }

    __shared__ float lS[NCHUNK][64];
    __shared__ float lA[NCHUNK][64];
    lS[ty][tx] = S;
    lA[ty][tx] = A;
    __syncthreads();

    if (ty == 0) {
        const float S0 = lS[0][tx], S1 = lS[1][tx], S2 = lS[2][tx], S3 = lS[3][tx];
        const float A0 = lA[0][tx], A1 = lA[1][tx], A2 = lA[2][tx], A3 = lA[3][tx];
        const float Stot = S0 + A0 * (S1 + A1 * (S2 + A2 * S3));
        const float Atot = A0 * A1 * A2 * A3;
        // gray = mean(rgb,rgb,rgb,opacity) = (3*S + (1 - prod(1-dens))) / 4
        const float gray = (3.0f * Stot + (1.0f - Atot)) * 0.25f;
        out[w * IMG_H + h] = gray;

        // wave-level max reduction (lanes 0..63 = the ty==0 wave)
        float m = gray;
        #pragma unroll
        for (int off = 32; off > 0; off >>= 1)
            m = fmaxf(m, __shfl_down(m, off));
        if (tx == 0)
            atomicMax(maxbits, __float_as_uint(m));  // gray >= 0: uint order == float order
    }
}

__global__ __launch_bounds__(256) void normalize_kernel(
    float* __restrict__ out, const unsigned int* __restrict__ maxbits)
{
    const int i = blockIdx.x * blockDim.x + threadIdx.x;
    const float m = __uint_as_float(*maxbits);
    out[i] = (out[i] + 1e-8f) / (m + 1e-8f);
}

extern "C" void kernel_launch(void* const* d_in, const int* in_sizes, int n_in,
                              void* d_out, int out_size, void* d_ws, size_t ws_size,
                              hipStream_t stream) {
    (void)in_sizes; (void)n_in; (void)out_size; (void)ws_size;
    const float* vol   = (const float*)d_in[0];
    const float* Rm    = (const float*)d_in[1];
    const float* Tv    = (const float*)d_in[2];
    const float* focal = (const float*)d_in[3];
    float* out = (float*)d_out;
    unsigned int* maxbits = (unsigned int*)d_ws;

    hipMemsetAsync(d_ws, 0, 4, stream);   // maxbits = 0 (valid: all gray >= 0)

    dim3 block(64, NCHUNK, 1);
    dim3 grid(IMG_W / 64, IMG_H, 1);
    render_kernel<<<grid, block, 0, stream>>>(vol, Rm, Tv, focal, out, maxbits);

    normalize_kernel<<<(IMG_W * IMG_H) / 256, 256, 0, stream>>>(out, maxbits);
}

// Round 2
// 115.145 us; speedup vs baseline: 1.1250x; 1.1250x over previous
//
#include <hip/hip_runtime.h>

#define IMG_W 256
#define IMG_H 256
#define N_PTS 320
#define VD 256
#define VH 256
#define VW 256
#define PX 8          // pixels (x) per block
#define NC 32         // depth chunks per ray
#define DSTEP (6.0f / (N_PTS - 1))

// Block: (PX, NC) = 256 threads. Wave = 8 px * 8 chunks.
__global__ __launch_bounds__(256) void render_kernel(
    const float* __restrict__ vol,    // (256,256,256) z-major
    const float* __restrict__ Rm,     // 3x3 row-major
    const float* __restrict__ Tv,     // 3
    const float* __restrict__ focal,  // 1
    float* __restrict__ out,          // out[w*IMG_H + h]
    unsigned int* __restrict__ maxbits)
{
    const int tx = threadIdx.x;            // 0..PX-1
    const int ty = threadIdx.y;            // 0..NC-1
    const int w  = blockIdx.x * PX + tx;   // pixel column (xs index)
    const int h  = blockIdx.y;             // pixel row (ys index)

    const float a  = 1.0f - 1.0f / IMG_W;
    const float gx = a - (2.0f * a / (IMG_W - 1)) * (float)w;
    const float gy = a - (2.0f * a / (IMG_H - 1)) * (float)h;

    const float f  = focal[0];
    const float ux = gx / f, uy = gy / f;

    const float R00 = Rm[0], R01 = Rm[1], R02 = Rm[2];
    const float R10 = Rm[3], R11 = Rm[4], R12 = Rm[5];
    const float R20 = Rm[6], R21 = Rm[7], R22 = Rm[8];
    const float Tx = Tv[0], Ty = Tv[1], Tz = Tv[2];

    // world coords affine in depth d
    const float Bx = R00 * ux + R01 * uy + R02;
    const float By = R10 * ux + R11 * uy + R12;
    const float Bz = R20 * ux + R21 * uy + R22;
    const float Ax = -(R00 * Tx + R01 * Ty + R02 * Tz);
    const float Ay = -(R10 * Tx + R11 * Ty + R12 * Tz);
    const float Az = -(R20 * Tx + R21 * Ty + R22 * Tz);

    const float voxel = 2.0f / 256.0f;
    const float hx = voxel * (VW - 1) * 0.5f;
    const float hy = voxel * (VH - 1) * 0.5f;
    const float hz = voxel * (VD - 1) * 0.5f;

    // voxel-space coords: fx = fAx + fBx*d
    const float sxc = 0.5f * (VW - 1) / hx, oxc = 0.5f * (VW - 1);
    const float syc = 0.5f * (VH - 1) / hy, oyc = 0.5f * (VH - 1);
    const float szc = 0.5f * (VD - 1) / hz, ozc = 0.5f * (VD - 1);
    const float fBx = Bx * sxc, fAx = Ax * sxc + oxc;
    const float fBy = By * syc, fAy = Ay * syc + oyc;
    const float fBz = Bz * szc, fAz = Az * szc + ozc;

    // ---- analytic ray/box slab clip: sample support needs fx in [-1, 256) ----
    float dlo = 3.0f, dhi = 9.0f;
    {
        const float lo = -1.0f, hi = 256.0f;
        #pragma unroll
        for (int dim = 0; dim < 3; ++dim) {
            const float fA = dim == 0 ? fAx : (dim == 1 ? fAy : fAz);
            const float fB = dim == 0 ? fBx : (dim == 1 ? fBy : fBz);
            if (fabsf(fB) > 1e-12f) {
                const float r = 1.0f / fB;
                const float t0 = (lo - fA) * r, t1 = (hi - fA) * r;
                dlo = fmaxf(dlo, fminf(t0, t1));
                dhi = fminf(dhi, fmaxf(t0, t1));
            } else if (fA < lo || fA >= hi) {
                dhi = -1.0f;  // empty
            }
        }
    }
    int pmin = 0, pmax = 0;
    if (dhi > dlo) {
        pmin = max(0, (int)floorf((dlo - 3.0f) / DSTEP) - 1);
        pmax = min(N_PTS, (int)ceilf((dhi - 3.0f) / DSTEP) + 2);
        if (pmax < pmin) pmax = pmin;
    }

    // dynamic chunking: equal share of the *clipped* range per chunk-thread
    const int len = pmax - pmin;
    const int plo = pmin + ((len * ty) >> 5);        // /NC
    const int phi = pmin + ((len * (ty + 1)) >> 5);

    float S = 0.0f;   // chunk partial weighted feature sum
    float A = 1.0f;   // chunk partial transmittance product

    #pragma unroll 2
    for (int p = plo; p < phi; ++p) {
        const float d = 3.0f + (float)p * DSTEP;

        const float fx = fmaf(fBx, d, fAx);
        const float fy = fmaf(fBy, d, fAy);
        const float fz = fmaf(fBz, d, fAz);

        const float flx = floorf(fx), fly = floorf(fy), flz = floorf(fz);
        const int ix0 = (int)flx, iy0 = (int)fly, iz0 = (int)flz;

        float dens = 0.0f, feat = 0.0f;
        if (ix0 >= -1 && ix0 < VW && iy0 >= -1 && iy0 < VH && iz0 >= -1 && iz0 < VD) {
            const float frx = fx - flx, fry = fy - fly, frz = fz - flz;
            float wx0 = 1.0f - frx, wx1 = frx;
            float wy0 = 1.0f - fry, wy1 = fry;
            float wz0 = 1.0f - frz, wz1 = frz;
            if (ix0 < 0)       wx0 = 0.0f;
            if (ix0 + 1 >= VW) wx1 = 0.0f;
            if (iy0 < 0)       wy0 = 0.0f;
            if (iy0 + 1 >= VH) wy1 = 0.0f;
            if (iz0 < 0)       wz0 = 0.0f;
            if (iz0 + 1 >= VD) wz1 = 0.0f;

            const int cx0 = max(ix0, 0), cx1 = min(ix0 + 1, VW - 1);
            const int cy0 = max(iy0, 0), cy1 = min(iy0 + 1, VH - 1);
            const int cz0 = max(iz0, 0), cz1 = min(iz0 + 1, VD - 1);

            const int zb0 = cz0 * (VH * VW), zb1 = cz1 * (VH * VW);
            const int yb0 = cy0 * VW,        yb1 = cy1 * VW;

            const float v000 = vol[zb0 + yb0 + cx0];
            const float v001 = vol[zb0 + yb0 + cx1];
            const float v010 = vol[zb0 + yb1 + cx0];
            const float v011 = vol[zb0 + yb1 + cx1];
            const float v100 = vol[zb1 + yb0 + cx0];
            const float v101 = vol[zb1 + yb0 + cx1];
            const float v110 = vol[zb1 + yb1 + cx0];
            const float v111 = vol[zb1 + yb1 + cx1];

            const float w00 = wy0 * wz0, w01 = wy1 * wz0;
            const float w10 = wy0 * wz1, w11 = wy1 * wz1;
            const float c000 = wx0 * w00, c001 = wx1 * w00;
            const float c010 = wx0 * w01, c011 = wx1 * w01;
            const float c100 = wx0 * w10, c101 = wx1 * w10;
            const float c110 = wx0 * w11, c111 = wx1 * w11;

            feat = c000 * v000 + c001 * v001 + c010 * v010 + c011 * v011
                 + c100 * v100 + c101 * v101 + c110 * v110 + c111 * v111;
            dens = 0.1f * (c000 + c001 + c010 + c011 + c100 + c101 + c110 + c111);
        }

        S = fmaf(dens * A, feat, S);   // (1+1e-10) rounds to 1.0f in f32
        A *= (1.0f - dens);
    }

    __shared__ float lS[NC][PX];
    __shared__ float lA[NC][PX];
    lS[ty][tx] = S;
    lA[ty][tx] = A;
    __syncthreads();

    if (ty == 0) {
        float Stot = 0.0f, Atot = 1.0f;
        #pragma unroll
        for (int c = 0; c < NC; ++c) {
            Stot = fmaf(Atot, lS[c][tx], Stot);
            Atot *= lA[c][tx];
        }
        const float gray = (3.0f * Stot + (1.0f - Atot)) * 0.25f;
        out[w * IMG_H + h] = gray;

        // max across the PX=8 active lanes (lanes 0..7); inactive-lane garbage
        // never propagates to lane 0 in this tree.
        float m = gray;
        m = fmaxf(m, __shfl_down(m, 4));
        m = fmaxf(m, __shfl_down(m, 2));
        m = fmaxf(m, __shfl_down(m, 1));
        if (tx == 0 && m > 0.0f)
            atomicMax(maxbits, __float_as_uint(m));  // gray >= 0
    }
}

__global__ __launch_bounds__(256) void normalize_kernel(
    float* __restrict__ out, const unsigned int* __restrict__ maxbits)
{
    const int i = blockIdx.x * blockDim.x + threadIdx.x;
    const float m = __uint_as_float(*maxbits);
    out[i] = (out[i] + 1e-8f) / (m + 1e-8f);
}

extern "C" void kernel_launch(void* const* d_in, const int* in_sizes, int n_in,
                              void* d_out, int out_size, void* d_ws, size_t ws_size,
                              hipStream_t stream) {
    (void)in_sizes; (void)n_in; (void)out_size; (void)ws_size;
    const float* vol   = (const float*)d_in[0];
    const float* Rm    = (const float*)d_in[1];
    const float* Tv    = (const float*)d_in[2];
    const float* focal = (const float*)d_in[3];
    float* out = (float*)d_out;
    unsigned int* maxbits = (unsigned int*)d_ws;

    hipMemsetAsync(d_ws, 0, 4, stream);

    dim3 block(PX, NC, 1);
    dim3 grid(IMG_W / PX, IMG_H, 1);
    render_kernel<<<grid, block, 0, stream>>>(vol, Rm, Tv, focal, out, maxbits);

    normalize_kernel<<<(IMG_W * IMG_H) / 256, 256, 0, stream>>>(out, maxbits);
}

// Round 3
// 108.025 us; speedup vs baseline: 1.1991x; 1.0659x over previous
//
#include <hip/hip_runtime.h>

#define IMG_W 256
#define IMG_H 256
#define N_PTS 320
#define VD 256
#define VH 256
#define VW 256
#define DSTEP (6.0f / (N_PTS - 1))
#define RPB 16   // rays per render block
#define CPR 16   // chunk-threads per ray

// ws layout (uint*): [0]=maxbits, [1]=active count, [2..] uint2 list {rayid|pmin<<16, len}

struct RayCoef { float fAx, fBx, fAy, fBy, fAz, fBz; };

__device__ __forceinline__ RayCoef ray_coef(int w, int h,
                                            const float* __restrict__ Rm,
                                            const float* __restrict__ Tv,
                                            const float* __restrict__ focal) {
    const float a  = 1.0f - 1.0f / IMG_W;
    const float gx = a - (2.0f * a / (IMG_W - 1)) * (float)w;
    const float gy = a - (2.0f * a / (IMG_H - 1)) * (float)h;
    const float f  = focal[0];
    const float ux = gx / f, uy = gy / f;
    const float R00 = Rm[0], R01 = Rm[1], R02 = Rm[2];
    const float R10 = Rm[3], R11 = Rm[4], R12 = Rm[5];
    const float R20 = Rm[6], R21 = Rm[7], R22 = Rm[8];
    const float Tx = Tv[0], Ty = Tv[1], Tz = Tv[2];
    const float Bx = R00 * ux + R01 * uy + R02;
    const float By = R10 * ux + R11 * uy + R12;
    const float Bz = R20 * ux + R21 * uy + R22;
    const float Ax = -(R00 * Tx + R01 * Ty + R02 * Tz);
    const float Ay = -(R10 * Tx + R11 * Ty + R12 * Tz);
    const float Az = -(R20 * Tx + R21 * Ty + R22 * Tz);
    const float voxel = 2.0f / 256.0f;
    const float hx = voxel * (VW - 1) * 0.5f;
    const float hy = voxel * (VH - 1) * 0.5f;
    const float hz = voxel * (VD - 1) * 0.5f;
    const float sxc = 0.5f * (VW - 1) / hx, oxc = 0.5f * (VW - 1);
    const float syc = 0.5f * (VH - 1) / hy, oyc = 0.5f * (VH - 1);
    const float szc = 0.5f * (VD - 1) / hz, ozc = 0.5f * (VD - 1);
    RayCoef rc;
    rc.fBx = Bx * sxc; rc.fAx = Ax * sxc + oxc;
    rc.fBy = By * syc; rc.fAy = Ay * syc + oyc;
    rc.fBz = Bz * szc; rc.fAz = Az * szc + ozc;
    return rc;
}

// exact sample range [pmin, pmin+len) outside of which dens == feat == 0
__device__ __forceinline__ void clip_ray(const RayCoef& rc, int& pmin, int& len) {
    float dlo = 3.0f, dhi = 9.0f;
    const float lo = -1.0f, hi = 256.0f;
    const float fA[3] = { rc.fAx, rc.fAy, rc.fAz };
    const float fB[3] = { rc.fBx, rc.fBy, rc.fBz };
    #pragma unroll
    for (int dim = 0; dim < 3; ++dim) {
        if (fabsf(fB[dim]) > 1e-12f) {
            const float r = 1.0f / fB[dim];
            const float t0 = (lo - fA[dim]) * r, t1 = (hi - fA[dim]) * r;
            dlo = fmaxf(dlo, fminf(t0, t1));
            dhi = fminf(dhi, fmaxf(t0, t1));
        } else if (fA[dim] < lo || fA[dim] >= hi) {
            dhi = -1.0f;
        }
    }
    pmin = 0; len = 0;
    if (dhi > dlo) {
        pmin = max(0, (int)floorf((dlo - 3.0f) / DSTEP) - 1);
        int pmax = min(N_PTS, (int)ceilf((dhi - 3.0f) / DSTEP) + 2);
        len = max(0, pmax - pmin);
    }
}

// one thread per ray: clip, zero-fill empty rays, append active rays to list
__global__ __launch_bounds__(256) void prep_kernel(
    const float* __restrict__ Rm, const float* __restrict__ Tv,
    const float* __restrict__ focal, float* __restrict__ out,
    unsigned int* __restrict__ wsu)
{
    const int w = threadIdx.x;      // xs index; 64 consecutive w per wave
    const int h = blockIdx.x;       // ys index
    const RayCoef rc = ray_coef(w, h, Rm, Tv, focal);
    int pmin, len;
    clip_ray(rc, pmin, len);

    const bool active = (len > 0);
    if (!active) out[w * IMG_H + h] = 0.0f;   // empty ray => gray == 0 exactly

    const unsigned long long mask = __ballot(active);
    const int lane = threadIdx.x & 63;
    const int cnt  = __popcll(mask);
    if (cnt) {
        const int leader = __ffsll(mask) - 1;
        unsigned int base = 0;
        if (lane == leader) base = atomicAdd(&wsu[1], (unsigned)cnt);
        base = __shfl(base, leader);
        if (active) {
            const int rank = __popcll(mask & ((1ull << lane) - 1ull));
            uint2 e;
            e.x = (unsigned)(h * IMG_W + w) | ((unsigned)pmin << 16);
            e.y = (unsigned)len;
            ((uint2*)(wsu + 2))[base + rank] = e;
        }
    }
}

// block (RPB rays, CPR chunks); grid sized for worst case, idle blocks exit fast
__global__ __launch_bounds__(256) void render_kernel(
    const float* __restrict__ vol, const float* __restrict__ Rm,
    const float* __restrict__ Tv, const float* __restrict__ focal,
    float* __restrict__ out, unsigned int* __restrict__ wsu)
{
    const unsigned count = wsu[1];
    if (blockIdx.x * RPB >= count) return;   // uniform early exit

    const int tx = threadIdx.x;              // ray slot 0..15
    const int ty = threadIdx.y;              // chunk    0..15
    const unsigned slot = blockIdx.x * RPB + tx;
    const bool valid = (slot < count);

    uint2 e = make_uint2(0u, 0u);
    if (valid) e = ((const uint2*)(wsu + 2))[slot];
    const int rayid = (int)(e.x & 0xffffu);
    const int pmin  = (int)(e.x >> 16);
    const int len   = (int)e.y;              // 0 for invalid slots
    const int w = rayid & (IMG_W - 1);
    const int h = rayid >> 8;

    const RayCoef rc = ray_coef(w, h, Rm, Tv, focal);

    const int plo = pmin + ((len * ty) >> 4);
    const int phi = pmin + ((len * (ty + 1)) >> 4);

    float S = 0.0f, A = 1.0f;
    for (int p = plo; p < phi; ++p) {
        const float d = 3.0f + (float)p * DSTEP;
        const float fx = fmaf(rc.fBx, d, rc.fAx);
        const float fy = fmaf(rc.fBy, d, rc.fAy);
        const float fz = fmaf(rc.fBz, d, rc.fAz);

        const float flx = floorf(fx), fly = floorf(fy), flz = floorf(fz);
        const int ix0 = (int)flx, iy0 = (int)fly, iz0 = (int)flz;

        float dens = 0.0f, feat = 0.0f;
        if (ix0 >= -1 && ix0 < VW && iy0 >= -1 && iy0 < VH && iz0 >= -1 && iz0 < VD) {
            const float frx = fx - flx, fry = fy - fly, frz = fz - flz;
            float wx0 = 1.0f - frx, wx1 = frx;
            float wy0 = 1.0f - fry, wy1 = fry;
            float wz0 = 1.0f - frz, wz1 = frz;
            if (ix0 < 0)       wx0 = 0.0f;
            if (ix0 + 1 >= VW) wx1 = 0.0f;
            if (iy0 < 0)       wy0 = 0.0f;
            if (iy0 + 1 >= VH) wy1 = 0.0f;
            if (iz0 < 0)       wz0 = 0.0f;
            if (iz0 + 1 >= VD) wz1 = 0.0f;

            const int cx0 = max(ix0, 0), cx1 = min(ix0 + 1, VW - 1);
            const int cy0 = max(iy0, 0), cy1 = min(iy0 + 1, VH - 1);
            const int cz0 = max(iz0, 0), cz1 = min(iz0 + 1, VD - 1);

            const int zb0 = cz0 * (VH * VW), zb1 = cz1 * (VH * VW);
            const int yb0 = cy0 * VW,        yb1 = cy1 * VW;

            const float v000 = vol[zb0 + yb0 + cx0];
            const float v001 = vol[zb0 + yb0 + cx1];
            const float v010 = vol[zb0 + yb1 + cx0];
            const float v011 = vol[zb0 + yb1 + cx1];
            const float v100 = vol[zb1 + yb0 + cx0];
            const float v101 = vol[zb1 + yb0 + cx1];
            const float v110 = vol[zb1 + yb1 + cx0];
            const float v111 = vol[zb1 + yb1 + cx1];

            const float w00 = wy0 * wz0, w01 = wy1 * wz0;
            const float w10 = wy0 * wz1, w11 = wy1 * wz1;
            const float c000 = wx0 * w00, c001 = wx1 * w00;
            const float c010 = wx0 * w01, c011 = wx1 * w01;
            const float c100 = wx0 * w10, c101 = wx1 * w10;
            const float c110 = wx0 * w11, c111 = wx1 * w11;

            feat = c000 * v000 + c001 * v001 + c010 * v010 + c011 * v011
                 + c100 * v100 + c101 * v101 + c110 * v110 + c111 * v111;
            dens = 0.1f * (c000 + c001 + c010 + c011 + c100 + c101 + c110 + c111);
        }

        S = fmaf(dens * A, feat, S);   // (1 + 1e-10) rounds to 1.0f
        A *= (1.0f - dens);
    }

    __shared__ float lS[CPR][RPB];
    __shared__ float lA[CPR][RPB];
    lS[ty][tx] = S;
    lA[ty][tx] = A;
    __syncthreads();

    if (ty == 0) {
        float Stot = 0.0f, Atot = 1.0f;
        #pragma unroll
        for (int c = 0; c < CPR; ++c) {
            Stot = fmaf(Atot, lS[c][tx], Stot);
            Atot *= lA[c][tx];
        }
        const float gray = (3.0f * Stot + (1.0f - Atot)) * 0.25f;
        if (valid) out[w * IMG_H + h] = gray;

        // block max over the 16 ty==0 lanes (garbage from lanes>=16 never reaches lane 0)
        float m = valid ? gray : 0.0f;
        m = fmaxf(m, __shfl_down(m, 8));
        m = fmaxf(m, __shfl_down(m, 4));
        m = fmaxf(m, __shfl_down(m, 2));
        m = fmaxf(m, __shfl_down(m, 1));
        if (tx == 0 && m > 0.0f)
            atomicMax(&wsu[0], __float_as_uint(m));   // gray >= 0
    }
}

__global__ __launch_bounds__(256) void normalize_kernel(
    float* __restrict__ out, const unsigned int* __restrict__ wsu)
{
    const int i = blockIdx.x * blockDim.x + threadIdx.x;
    const float m = __uint_as_float(wsu[0]);
    out[i] = (out[i] + 1e-8f) / (m + 1e-8f);
}

extern "C" void kernel_launch(void* const* d_in, const int* in_sizes, int n_in,
                              void* d_out, int out_size, void* d_ws, size_t ws_size,
                              hipStream_t stream) {
    (void)in_sizes; (void)n_in; (void)out_size; (void)ws_size;
    const float* vol   = (const float*)d_in[0];
    const float* Rm    = (const float*)d_in[1];
    const float* Tv    = (const float*)d_in[2];
    const float* focal = (const float*)d_in[3];
    float* out = (float*)d_out;
    unsigned int* wsu = (unsigned int*)d_ws;

    hipMemsetAsync(d_ws, 0, 8, stream);   // maxbits = 0, count = 0

    prep_kernel<<<IMG_H, IMG_W, 0, stream>>>(Rm, Tv, focal, out, wsu);

    dim3 rblock(RPB, CPR, 1);
    dim3 rgrid((IMG_W * IMG_H + RPB - 1) / RPB, 1, 1);  // worst case; idle blocks exit
    render_kernel<<<rgrid, rblock, 0, stream>>>(vol, Rm, Tv, focal, out, wsu);

    normalize_kernel<<<(IMG_W * IMG_H) / 256, 256, 0, stream>>>(out, wsu);
}